// Round 3
// baseline (229.596 us; speedup 1.0000x reference)
//
#include <hip/hip_runtime.h>
#include <stdint.h>
#include <math.h>

#define N_NODES 50000
#define N_EDGES 1500000
#define HDIM 128
#define TDIM 100
#define KPAD 512         // 484 padded to multiple of 32
#define SM 32            // nodes per stage block
#define GM 64            // nodes per gemm block

typedef __attribute__((ext_vector_type(8))) short short8v;
typedef __attribute__((ext_vector_type(4))) float f32x4;

__device__ __forceinline__ unsigned short f2bf(float x) {
    unsigned int u = __float_as_uint(x);
    return (unsigned short)((u + 0x7fffu + ((u >> 16) & 1u)) >> 16);
}
__device__ __forceinline__ float sigmoidf_(float x) { return 1.0f / (1.0f + __expf(-x)); }
__device__ __forceinline__ float tanhf_(float x) { return 2.0f / (1.0f + __expf(-2.0f * x)) - 1.0f; }

__global__ void init_keys_kernel(unsigned long long* __restrict__ keys) {
    int i = blockIdx.x * 256 + threadIdx.x;
    if (i < N_NODES) keys[i] = 0ULL;
}

__global__ void scan_edges_kernel(const int* __restrict__ dst,
                                  const float* __restrict__ edge_ts,
                                  unsigned long long* __restrict__ keys) {
    int e = blockIdx.x * 256 + threadIdx.x;
    if (e < N_EDGES) {
        // ts >= 0 -> IEEE bits order-preserving; +1 so key==0 means "no msg";
        // low word tie-breaks toward max edge index (matches reference).
        unsigned long long key =
            ((unsigned long long)__float_as_uint(edge_ts[e]) << 32) | (unsigned int)(e + 1);
        atomicMax(&keys[dst[e]], key);
    }
}

__global__ void convert_w_kernel(const float* __restrict__ Wih, const float* __restrict__ Whh,
                                 unsigned short* __restrict__ wb1, unsigned short* __restrict__ wb2) {
    int idx = blockIdx.x * 256 + threadIdx.x;
    if (idx < 384 * KPAD) {
        int n = idx >> 9, k = idx & (KPAD - 1);
        wb1[idx] = (k < 484) ? f2bf(Wih[n * 484 + k]) : (unsigned short)0;
    } else {
        int j = idx - 384 * KPAD;
        if (j < 384 * HDIM) wb2[j] = f2bf(Whh[j]);
    }
}

// Build m_bar rows [mem_s[src] | mem_s[n] | ef[w] | tenc | 0-pad] as bf16,
// PRE-SWIZZLED (16B-group g of row r stored at g ^ (r&7)) so the gemm kernel
// can copy rows linearly into LDS and read with the same XOR.
__global__ __launch_bounds__(256)
void stage_kernel(const int* __restrict__ src, const float* __restrict__ edge_ts,
                  const float* __restrict__ ef, const float* __restrict__ mem,
                  const float* __restrict__ lut, const float* __restrict__ tw,
                  const float* __restrict__ tb, const unsigned long long* __restrict__ keys,
                  unsigned short* __restrict__ Abuf, int* __restrict__ hasbuf,
                  float* __restrict__ out) {
    __shared__ int sh_src[SM], sh_e[SM];
    __shared__ float sh_delta[SM];
    const int tid = threadIdx.x;
    const int base = blockIdx.x * SM;
    if (tid < SM) {
        int n = base + tid;
        int e = 0, s = 0;
        float delta = 0.f;
        if (n < N_NODES) {
            unsigned long long key = keys[n];
            int has = (key != 0ULL);
            e = has ? (int)((unsigned int)key - 1u) : 0;
            s = src[e];
            float tv = edge_ts[e];
            delta = tv - lut[s];
            hasbuf[n] = has;
            out[(size_t)N_NODES * HDIM + n] = has ? tv : lut[n];
        }
        sh_src[tid] = s; sh_e[tid] = e; sh_delta[tid] = delta;
    }
    __syncthreads();
    const int i = tid >> 3, l8 = tid & 7;     // 8 threads per node
    const int n = base + i;
    if (n >= N_NODES) return;
    const int s = sh_src[i], e = sh_e[i];
    const float d = sh_delta[i];
    const int swg = i & 7;
    unsigned short* Arow = Abuf + (size_t)n * KPAD;
    #pragma unroll
    for (int p = 0; p < 8; ++p) {
        const int gk = p * 8 + l8, k0 = gk * 8;   // 16B group 0..63
        float f[8];
        if (k0 < 384) {
            const float* sp = (k0 < 128) ? mem + (size_t)s * HDIM + k0
                            : (k0 < 256) ? mem + (size_t)n * HDIM + (k0 - 128)
                                         : ef + (size_t)e * HDIM + (k0 - 256);
            float4 v0 = *(const float4*)sp;
            float4 v1 = *(const float4*)(sp + 4);
            f[0]=v0.x; f[1]=v0.y; f[2]=v0.z; f[3]=v0.w;
            f[4]=v1.x; f[5]=v1.y; f[6]=v1.z; f[7]=v1.w;
        } else {
            #pragma unroll
            for (int j2 = 0; j2 < 8; ++j2) {
                int q = k0 - 384 + j2;
                f[j2] = (q < TDIM) ? cosf(fmaf(d, tw[q], tb[q])) : 0.f;
            }
        }
        uint4 pk;
        pk.x = (unsigned)f2bf(f[0]) | ((unsigned)f2bf(f[1]) << 16);
        pk.y = (unsigned)f2bf(f[2]) | ((unsigned)f2bf(f[3]) << 16);
        pk.z = (unsigned)f2bf(f[4]) | ((unsigned)f2bf(f[5]) << 16);
        pk.w = (unsigned)f2bf(f[6]) | ((unsigned)f2bf(f[7]) << 16);
        *(uint4*)&Arow[(size_t)(gk ^ swg) * 8] = pk;
    }
}

// BM=64, 8 waves (2 M-halves x 4 N-quarters). Wave: 32 rows x (32 cols per gate).
__global__ __launch_bounds__(512, 4)
void gemm_kernel(const unsigned short* __restrict__ Abuf,
                 const unsigned short* __restrict__ wb1,   // [384][512] bf16
                 const unsigned short* __restrict__ wb2,   // [384][128] bf16
                 const float* __restrict__ bih, const float* __restrict__ bhh,
                 const float* __restrict__ mem, const int* __restrict__ hasbuf,
                 float* __restrict__ out) {
    __shared__ unsigned short Alds[GM * KPAD];   // 64 KB
    const int tid = threadIdx.x;
    const int base = blockIdx.x * GM;

    // ---- stage A tile: linear 64 KB copy (already swizzled in Abuf) ----
    {
        const uint4* g = (const uint4*)(Abuf + (size_t)base * KPAD);
        uint4 v[8];
        #pragma unroll
        for (int i = 0; i < 8; ++i) v[i] = g[i * 512 + tid];
        uint4* lds = (uint4*)Alds;
        #pragma unroll
        for (int i = 0; i < 8; ++i) lds[i * 512 + tid] = v[i];
    }
    __syncthreads();

    const int w = tid >> 6, l = tid & 63;
    const int mh = w >> 2, nq = w & 3;
    const int lr = l & 15, lh = l >> 4;

    const f32x4 fzero = {0.f, 0.f, 0.f, 0.f};
    f32x4 acc[3][2][2];   // [gate r,z,n(i-part)][nf][mf]
    f32x4 acch[2][2];     // n-gate h-part
    #pragma unroll
    for (int g3 = 0; g3 < 3; ++g3)
        #pragma unroll
        for (int nf = 0; nf < 2; ++nf)
            #pragma unroll
            for (int mf = 0; mf < 2; ++mf) acc[g3][nf][mf] = fzero;
    #pragma unroll
    for (int nf = 0; nf < 2; ++nf)
        #pragma unroll
        for (int mf = 0; mf < 2; ++mf) acch[nf][mf] = fzero;

    // GEMM1: gi = A(K=512) @ W_ih^T
    #pragma unroll 4
    for (int kt = 0; kt < KPAD / 32; ++kt) {
        const int k0 = kt * 32;
        short8v a[2];
        #pragma unroll
        for (int mf = 0; mf < 2; ++mf) {
            const int row = mh * 32 + mf * 16 + lr;
            a[mf] = *(const short8v*)&Alds[row * KPAD + ((k0 + lh * 8) ^ ((row & 7) << 3))];
        }
        #pragma unroll
        for (int g3 = 0; g3 < 3; ++g3)
            #pragma unroll
            for (int nf = 0; nf < 2; ++nf) {
                const int nrow = g3 * 128 + nq * 32 + nf * 16 + lr;
                short8v b = *(const short8v*)&wb1[(size_t)nrow * KPAD + k0 + lh * 8];
                #pragma unroll
                for (int mf = 0; mf < 2; ++mf)
                    acc[g3][nf][mf] = __builtin_amdgcn_mfma_f32_16x16x32_bf16(
                        a[mf], b, acc[g3][nf][mf], 0, 0, 0);
            }
    }
    // GEMM2: gh = mem_s @ W_hh^T (A slice k=128..256)
    #pragma unroll
    for (int kt = 0; kt < 4; ++kt) {
        const int kA = 128 + kt * 32;
        short8v a[2];
        #pragma unroll
        for (int mf = 0; mf < 2; ++mf) {
            const int row = mh * 32 + mf * 16 + lr;
            a[mf] = *(const short8v*)&Alds[row * KPAD + ((kA + lh * 8) ^ ((row & 7) << 3))];
        }
        #pragma unroll
        for (int g3 = 0; g3 < 3; ++g3)
            #pragma unroll
            for (int nf = 0; nf < 2; ++nf) {
                const int nrow = g3 * 128 + nq * 32 + nf * 16 + lr;
                short8v b = *(const short8v*)&wb2[(size_t)nrow * HDIM + kt * 32 + lh * 8];
                #pragma unroll
                for (int mf = 0; mf < 2; ++mf) {
                    if (g3 < 2)
                        acc[g3][nf][mf] = __builtin_amdgcn_mfma_f32_16x16x32_bf16(
                            a[mf], b, acc[g3][nf][mf], 0, 0, 0);
                    else
                        acch[nf][mf] = __builtin_amdgcn_mfma_f32_16x16x32_bf16(
                            a[mf], b, acch[nf][mf], 0, 0, 0);
                }
            }
    }

    // ---- GRU epilogue ----
    #pragma unroll
    for (int mf = 0; mf < 2; ++mf)
        #pragma unroll
        for (int nf = 0; nf < 2; ++nf) {
            const int c = nq * 32 + nf * 16 + lr;
            const float b_r = bih[c] + bhh[c];
            const float b_z = bih[HDIM + c] + bhh[HDIM + c];
            const float bi_n = bih[2 * HDIM + c];
            const float bh_n = bhh[2 * HDIM + c];
            #pragma unroll
            for (int ii = 0; ii < 4; ++ii) {
                const int row = mh * 32 + mf * 16 + lh * 4 + ii;
                const int node = base + row;
                if (node >= N_NODES) continue;
                const float r = sigmoidf_(acc[0][nf][mf][ii] + b_r);
                const float z = sigmoidf_(acc[1][nf][mf][ii] + b_z);
                const float ng = tanhf_(acc[2][nf][mf][ii] + bi_n +
                                        r * (acch[nf][mf][ii] + bh_n));
                const float h = mem[(size_t)node * HDIM + c];
                out[(size_t)node * HDIM + c] =
                    hasbuf[node] ? (1.f - z) * ng + z * h : h;
            }
        }
}

extern "C" void kernel_launch(void* const* d_in, const int* in_sizes, int n_in,
                              void* d_out, int out_size, void* d_ws, size_t ws_size,
                              hipStream_t stream) {
    const int* src       = (const int*)d_in[0];
    const int* dst       = (const int*)d_in[1];
    const float* edge_ts = (const float*)d_in[2];
    const float* ef      = (const float*)d_in[3];
    const float* mem     = (const float*)d_in[4];
    const float* lut     = (const float*)d_in[5];
    const float* tw      = (const float*)d_in[6];
    const float* tb      = (const float*)d_in[7];
    const float* Wih     = (const float*)d_in[8];
    const float* Whh     = (const float*)d_in[9];
    const float* bih     = (const float*)d_in[10];
    const float* bhh     = (const float*)d_in[11];
    float* out = (float*)d_out;

    char* ws = (char*)d_ws;
    unsigned long long* keys = (unsigned long long*)ws;          // 400000 B (pad to 512K)
    unsigned short* wb1 = (unsigned short*)(ws + 524288);        // 393216 B
    unsigned short* wb2 = (unsigned short*)(ws + 917504);        //  98304 B
    int* hasbuf         = (int*)(ws + 1015808);                  // 200192 B
    unsigned short* Abuf = (unsigned short*)(ws + 1216000);      // 50048*512*2 B

    init_keys_kernel<<<(N_NODES + 255) / 256, 256, 0, stream>>>(keys);
    scan_edges_kernel<<<(N_EDGES + 255) / 256, 256, 0, stream>>>(dst, edge_ts, keys);
    convert_w_kernel<<<(384 * KPAD + 384 * HDIM + 255) / 256, 256, 0, stream>>>(
        Wih, Whh, wb1, wb2);
    stage_kernel<<<(N_NODES + SM - 1) / SM, 256, 0, stream>>>(
        src, edge_ts, ef, mem, lut, tw, tb, keys, Abuf, hasbuf, out);
    gemm_kernel<<<(N_NODES + GM - 1) / GM, 512, 0, stream>>>(
        Abuf, wb1, wb2, bih, bhh, mem, hasbuf, out);
}